// Round 8
// baseline (89.654 us; speedup 1.0000x reference)
//
#include <hip/hip_runtime.h>
#include <hip/hip_bf16.h>
#include <cstdint>
#include <cstddef>

#define B_ 8
#define T_ 2048
#define E_ 1024
#define D_ 64

typedef __attribute__((ext_vector_type(8))) short bf16x8;
typedef __attribute__((ext_vector_type(4))) float f32x4;
typedef __attribute__((ext_vector_type(16))) float f32x16;
typedef __attribute__((ext_vector_type(4))) unsigned short u16x4;

#define QSCALE 0.1803368801111204f  // 0.125 * log2(e)

__device__ __forceinline__ short f2bf(float f){
    __hip_bfloat16 h = __float2bfloat16(f);
    return *reinterpret_cast<short*>(&h);
}

__device__ __forceinline__ bf16x8 cvt8v(const f32x4 a, const f32x4 b){
    bf16x8 r;
    r[0]=f2bf(a[0]); r[1]=f2bf(a[1]); r[2]=f2bf(a[2]); r[3]=f2bf(a[3]);
    r[4]=f2bf(b[0]); r[5]=f2bf(b[1]); r[6]=f2bf(b[2]); r[7]=f2bf(b[3]);
    return r;
}

// ---------- W -> MFMA-fragment-linear layout (unchanged) ----------
__global__ __launch_bounds__(256) void wconv_kernel(
    const float* __restrict__ Wq, const float* __restrict__ Wk,
    const float* __restrict__ Wv, __hip_bfloat16* __restrict__ Wfrag)
{
    const int g = blockIdx.x*256 + threadIdx.x;   // [0, 24576)
    const int l = g & 63;
    const int ntg = (g >> 6) % 6;
    const int cg = g / 384;
    const int n = ntg*32 + (l & 31);
    const int m = n >> 6;
    const int ncol = n & 63;
    const float* W = (m==0) ? Wq : (m==1) ? Wk : Wv;
    const float sc = (m==0) ? QSCALE : 1.0f;
    const int k0 = cg*16 + (l>>5)*8;
    bf16x8 r;
    #pragma unroll
    for (int j=0;j<8;++j)
        r[j] = f2bf(W[(size_t)(k0+j)*64 + ncol] * sc);
    *reinterpret_cast<bf16x8*>(Wfrag + (size_t)g*8) = r;
}

// ---------- QKV projection v4 (UNCHANGED from R7) ----------
__global__ __launch_bounds__(384, 3) void proj_kernel(
    const float* __restrict__ x, const __hip_bfloat16* __restrict__ Wfrag,
    __hip_bfloat16* __restrict__ Qo, __hip_bfloat16* __restrict__ Ko,
    __hip_bfloat16* __restrict__ VTg)
{
    __shared__ __align__(16) unsigned short xs[2][32*64];   // 8 KB dbuf, bf16, XOR-swizzled
    __shared__ float vt[32*65];                             // 8.3 KB V-transpose scratch
    const int tid = threadIdx.x;
    const int w = tid>>6, l = tid&63;
    const int l31 = l&31, kg = l>>5;
    const float* xp = x + (size_t)blockIdx.x*32*E_;

    f32x16 acc;
    #pragma unroll
    for (int j=0;j<16;++j) acc[j]=0.f;

    const bf16x8* Wfp = reinterpret_cast<const bf16x8*>(Wfrag);

    bf16x8 btA[4], btB[4];
    #pragma unroll
    for (int c=0;c<4;++c)
        btA[c] = Wfp[(size_t)(((0*4+c)*6 + w)*64 + l)];

    const int srow = tid>>3, sc8 = tid&7;   // stager coords (tid<256)

    // prologue: stage k-slice 0 as bf16
    if (tid < 256){
        f32x4 v0 = *reinterpret_cast<const f32x4*>(xp + (size_t)srow*E_ + sc8*8);
        f32x4 v1 = *reinterpret_cast<const f32x4*>(xp + (size_t)srow*E_ + sc8*8 + 4);
        *reinterpret_cast<bf16x8*>((char*)&xs[0][0] + srow*128 + ((sc8*16) ^ ((srow&7)<<4))) = cvt8v(v0, v1);
    }
    __syncthreads();

#define PSTEP(T, BC, BN)                                                       \
    {                                                                          \
        const int t = (T);                                                     \
        if (t+1 < 16){                                                         \
            _Pragma("unroll")                                                  \
            for (int c=0;c<4;++c)                                              \
                BN[c] = Wfp[(size_t)((((t+1)*4+c)*6 + w)*64 + l)];             \
        }                                                                      \
        f32x4 xa0, xa1;                                                        \
        if (t+1 < 16 && tid < 256){                                            \
            xa0 = *reinterpret_cast<const f32x4*>(xp + (size_t)srow*E_ + (t+1)*64 + sc8*8);     \
            xa1 = *reinterpret_cast<const f32x4*>(xp + (size_t)srow*E_ + (t+1)*64 + sc8*8 + 4); \
        }                                                                      \
        const char* xb = (const char*)&xs[t&1][0];                             \
        _Pragma("unroll")                                                      \
        for (int c=0;c<4;++c){                                                 \
            bf16x8 af = *reinterpret_cast<const bf16x8*>(xb + l31*128 + (((c*32 + kg*16)) ^ ((l31&7)<<4))); \
            acc = __builtin_amdgcn_mfma_f32_32x32x16_bf16(af, BC[c], acc, 0,0,0); \
        }                                                                      \
        if (t+1 < 16){                                                         \
            if (tid < 256)                                                     \
                *reinterpret_cast<bf16x8*>((char*)&xs[(t+1)&1][0] + srow*128 + ((sc8*16) ^ ((srow&7)<<4))) = cvt8v(xa0, xa1); \
            __syncthreads();                                                   \
        }                                                                      \
    }

    for (int t2=0; t2<8; ++t2){
        PSTEP(2*t2,   btA, btB)
        PSTEP(2*t2+1, btB, btA)
    }
#undef PSTEP

    // ---- epilogue: waves 0,1 -> Q; 2,3 -> K; 4,5 -> V (transposed via LDS) ----
    const size_t rowBase = (size_t)blockIdx.x*32;
    const int mat = w>>1;
    const int col = (w&1)*32 + l31;
    if (mat < 2){
        __hip_bfloat16* dst = (mat==0) ? Qo : Ko;
        #pragma unroll
        for (int reg=0; reg<16; ++reg){
            const int mr = (reg&3) + 8*(reg>>2) + 4*kg;
            dst[(rowBase + mr)*64 + col] = __float2bfloat16(acc[reg]);
        }
    }
    if (mat == 2){
        #pragma unroll
        for (int reg=0; reg<16; ++reg){
            const int mr = (reg&3) + 8*(reg>>2) + 4*kg;
            vt[mr*65 + col] = acc[reg];
        }
    }
    __syncthreads();
    if (tid < 256){
        const int bb = blockIdx.x >> 6;
        const int t0 = (blockIdx.x & 63)*32;
        const int d = tid>>2, rseg = tid&3;
        bf16x8 pk;
        #pragma unroll
        for (int j=0;j<8;++j)
            pk[j] = f2bf(vt[(rseg*8+j)*65 + d]);
        *reinterpret_cast<bf16x8*>(VTg + (size_t)bb*64*T_ + (size_t)d*T_ + t0 + rseg*8) = pk;
    }
}

// ---------- flash attention v4 (UNCHANGED from R6/R7) ----------
__global__ __launch_bounds__(256, 2) void fattn_kernel(
    const __hip_bfloat16* __restrict__ Qg, const __hip_bfloat16* __restrict__ Kg,
    const __hip_bfloat16* __restrict__ VTg, float* __restrict__ out)
{
    __shared__ __align__(16) unsigned short Pl[4][16*64];   // 8 KB per-wave P
    __shared__ float Morg[4][2][16];
    __shared__ float Lorg[4][2][16];
    __shared__ __align__(16) float Oorg[4][2][16*64];       // 32 KB partials

    const int tid = threadIdx.x;
    const int w = tid>>6, l = tid&63;
    const int l15 = l&15, lg = l>>4;

    const int b = blockIdx.x & 7;          // XCD-batch affinity
    const int p = blockIdx.x >> 3;         // 0..63
    const int sA = p, sB = 127 - p;
    const int nA = (sA>>2) + 1, nB = (sB>>2) + 1;
    const int NU = nA + nB;                // == 33
    const size_t batchoff = (size_t)b * T_ * 64;
    const __hip_bfloat16* Kb = Kg + batchoff;
    const __hip_bfloat16* Vb = VTg + (size_t)b*64*T_;
    char* pw = (char*)&Pl[w][0];

    const int qrA = sA*16 + l15, qrB = sB*16 + l15;
    const bf16x8 qA0 = *reinterpret_cast<const bf16x8*>(Qg + batchoff + (size_t)qrA*64 + lg*8);
    const bf16x8 qA1 = *reinterpret_cast<const bf16x8*>(Qg + batchoff + (size_t)qrA*64 + 32 + lg*8);
    const bf16x8 qB0 = *reinterpret_cast<const bf16x8*>(Qg + batchoff + (size_t)qrB*64 + lg*8);
    const bf16x8 qB1 = *reinterpret_cast<const bf16x8*>(Qg + batchoff + (size_t)qrB*64 + 32 + lg*8);

    f32x4 oA[4], oB[4];
    #pragma unroll
    for (int i=0;i<4;++i){ oA[i] = (f32x4){0.f,0.f,0.f,0.f}; oB[i] = (f32x4){0.f,0.f,0.f,0.f}; }
    float mA = -1e30f, lA = 0.f, mB = -1e30f, lB = 0.f;

    bf16x8 kf[8], vf[8];

    {
        const int u0 = w;
        const int kv0 = (u0 < nA ? u0 : u0 - nA) * 64;
        #pragma unroll
        for (int ks=0;ks<2;++ks)
            #pragma unroll
            for (int nt=0;nt<4;++nt)
                kf[ks*4+nt] = *reinterpret_cast<const bf16x8*>(Kb + (size_t)(kv0 + nt*16 + l15)*64 + ks*32 + lg*8);
    }

    auto body = [&](f32x4 (&o)[4], float &mrun, float &lrun,
                    const bf16x8 &qf0, const bf16x8 &qf1,
                    int qrow, int kv0, bool diag, bool hasN, int kv0n)
    {
        f32x4 s4[4];
        #pragma unroll
        for (int nt=0;nt<4;++nt) s4[nt] = (f32x4){0.f,0.f,0.f,0.f};
        __builtin_amdgcn_s_setprio(1);
        #pragma unroll
        for (int ks=0;ks<2;++ks){
            const bf16x8 qf = ks ? qf1 : qf0;
            #pragma unroll
            for (int nt=0;nt<4;++nt)
                s4[nt] = __builtin_amdgcn_mfma_f32_16x16x32_bf16(kf[ks*4+nt], qf, s4[nt], 0,0,0);
        }
        __builtin_amdgcn_s_setprio(0);

        if (hasN){
            #pragma unroll
            for (int ks=0;ks<2;++ks)
                #pragma unroll
                for (int nt=0;nt<4;++nt)
                    kf[ks*4+nt] = *reinterpret_cast<const bf16x8*>(Kb + (size_t)(kv0n + nt*16 + l15)*64 + ks*32 + lg*8);
        }

        if (diag){
            #pragma unroll
            for (int nt=0;nt<4;++nt)
                #pragma unroll
                for (int rr=0;rr<4;++rr){
                    const int kv = kv0 + nt*16 + lg*4 + rr;
                    if (kv > qrow) s4[nt][rr] = -1e30f;
                }
        }

        float pm;
        {
            float m0 = fmaxf(fmaxf(s4[0][0],s4[0][1]), fmaxf(s4[0][2],s4[0][3]));
            float m1 = fmaxf(fmaxf(s4[1][0],s4[1][1]), fmaxf(s4[1][2],s4[1][3]));
            float m2 = fmaxf(fmaxf(s4[2][0],s4[2][1]), fmaxf(s4[2][2],s4[2][3]));
            float m3 = fmaxf(fmaxf(s4[3][0],s4[3][1]), fmaxf(s4[3][2],s4[3][3]));
            pm = fmaxf(fmaxf(m0,m1), fmaxf(m2,m3));
        }
        pm = fmaxf(pm, __shfl_xor(pm, 16));
        pm = fmaxf(pm, __shfl_xor(pm, 32));
        if (pm > mrun + 8.0f){
            const float scl = exp2f(mrun - pm);
            mrun = pm; lrun *= scl;
            #pragma unroll
            for (int dt=0;dt<4;++dt)
                #pragma unroll
                for (int j=0;j<4;++j) o[dt][j] *= scl;
        }
        float rs = 0.f;
        #pragma unroll
        for (int nt=0;nt<4;++nt)
            #pragma unroll
            for (int rr=0;rr<4;++rr){
                const float pv = exp2f(s4[nt][rr] - mrun);
                s4[nt][rr] = pv; rs += pv;
            }
        rs += __shfl_xor(rs, 16);
        rs += __shfl_xor(rs, 32);
        lrun += rs;

        #pragma unroll
        for (int nt=0;nt<4;++nt){
            u16x4 pk;
            #pragma unroll
            for (int rr=0;rr<4;++rr) pk[rr] = (unsigned short)f2bf(s4[nt][rr]);
            *reinterpret_cast<u16x4*>(pw + l15*128 + ((nt*32 + lg*8) ^ ((l15&7)<<4))) = pk;
        }

        __builtin_amdgcn_s_setprio(1);
        #pragma unroll
        for (int ks=0;ks<2;++ks){
            bf16x8 pf = *reinterpret_cast<const bf16x8*>(pw + l15*128 + ((ks*64 + lg*16) ^ ((l15&7)<<4)));
            #pragma unroll
            for (int dt=0;dt<4;++dt)
                o[dt] = __builtin_amdgcn_mfma_f32_16x16x32_bf16(vf[ks*4+dt], pf, o[dt], 0,0,0);
        }
        __builtin_amdgcn_s_setprio(0);
    };

    for (int u = w; u < NU; u += 4){
        const bool isA = (u < nA);
        const int kvt = isA ? u : (u - nA);
        const int kv0 = kvt*64;
        const bool diag = isA ? (kvt == nA-1) : (kvt == nB-1);

        #pragma unroll
        for (int ks=0;ks<2;++ks)
            #pragma unroll
            for (int dt=0;dt<4;++dt)
                vf[ks*4+dt] = *reinterpret_cast<const bf16x8*>(Vb + (size_t)(dt*16+l15)*T_ + kv0 + ks*32 + lg*8);

        const int un = u + 4;
        const bool hasN = un < NU;
        const int kv0n = hasN ? ((un < nA ? un : un - nA) * 64) : 0;

        if (isA) body(oA, mA, lA, qA0, qA1, qrA, kv0, diag, hasN, kv0n);
        else     body(oB, mB, lB, qB0, qB1, qrB, kv0, diag, hasN, kv0n);
    }

    #pragma unroll
    for (int dt=0;dt<4;++dt){
        *reinterpret_cast<f32x4*>(&Oorg[w][0][l15*64 + dt*16 + lg*4]) = oA[dt];
        *reinterpret_cast<f32x4*>(&Oorg[w][1][l15*64 + dt*16 + lg*4]) = oB[dt];
    }
    if (lg == 0){
        Morg[w][0][l15] = mA; Lorg[w][0][l15] = lA;
        Morg[w][1][l15] = mB; Lorg[w][1][l15] = lB;
    }
    __syncthreads();
    {
        const int h = tid>>7, q = (tid>>3)&15, d0 = (tid&7)*8;
        const float m0=Morg[0][h][q], m1=Morg[1][h][q], m2=Morg[2][h][q], m3=Morg[3][h][q];
        const float M = fmaxf(fmaxf(m0,m1), fmaxf(m2,m3));
        const float a0=exp2f(m0-M), a1=exp2f(m1-M), a2=exp2f(m2-M), a3=exp2f(m3-M);
        const float L = a0*Lorg[0][h][q] + a1*Lorg[1][h][q] + a2*Lorg[2][h][q] + a3*Lorg[3][h][q];
        const float inv = 1.0f / L;
        const int s = h ? sB : sA;
        float* op = out + batchoff + (size_t)(s*16 + q)*64 + d0;
        #pragma unroll
        for (int j=0;j<8;++j){
            const float v = a0*Oorg[0][h][q*64+d0+j] + a1*Oorg[1][h][q*64+d0+j]
                          + a2*Oorg[2][h][q*64+d0+j] + a3*Oorg[3][h][q*64+d0+j];
            op[j] = v * inv;
        }
    }
}

extern "C" void kernel_launch(void* const* d_in, const int* in_sizes, int n_in,
                              void* d_out, int out_size, void* d_ws, size_t ws_size,
                              hipStream_t stream) {
    const float* x  = (const float*)d_in[0];
    const float* Wq = (const float*)d_in[1];
    const float* Wk = (const float*)d_in[2];
    const float* Wv = (const float*)d_in[3];
    float* out = (float*)d_out;

    __hip_bfloat16* Wfrag = (__hip_bfloat16*)d_ws;              // 384 KB
    __hip_bfloat16* Qb  = Wfrag + (size_t)24576*8;              // [B*T,64] (pre-scaled)
    __hip_bfloat16* Kb  = Qb + (size_t)B_*T_*64;                // [B*T,64]
    __hip_bfloat16* VTb = Kb + (size_t)B_*T_*64;                // [B][64][T]

    wconv_kernel<<<96, 256, 0, stream>>>(Wq, Wk, Wv, Wfrag);
    proj_kernel<<<512, 384, 0, stream>>>(x, Wfrag, Qb, Kb, VTb);
    // MEASUREMENT: fattn launched twice (idempotent). fattn_dur = dur_R8 - dur_R7.
    fattn_kernel<<<512, 256, 0, stream>>>(Qb, Kb, VTb, out);
    fattn_kernel<<<512, 256, 0, stream>>>(Qb, Kb, VTb, out);
}

// Round 9
// 44.158 us; speedup vs baseline: 2.0303x; 2.0303x over previous
//
#include <hip/hip_runtime.h>
#include <hip/hip_bf16.h>
#include <cstdint>
#include <cstddef>

#define B_ 8
#define T_ 2048
#define E_ 1024
#define D_ 64

typedef __attribute__((ext_vector_type(8))) short bf16x8;
typedef __attribute__((ext_vector_type(4))) float f32x4;
typedef __attribute__((ext_vector_type(16))) float f32x16;
typedef __attribute__((ext_vector_type(4))) unsigned short u16x4;

#define QSCALE 0.1803368801111204f  // 0.125 * log2(e)

__device__ __forceinline__ short f2bf(float f){
    __hip_bfloat16 h = __float2bfloat16(f);
    return *reinterpret_cast<short*>(&h);
}

__device__ __forceinline__ bf16x8 cvt8v(const f32x4 a, const f32x4 b){
    bf16x8 r;
    r[0]=f2bf(a[0]); r[1]=f2bf(a[1]); r[2]=f2bf(a[2]); r[3]=f2bf(a[3]);
    r[4]=f2bf(b[0]); r[5]=f2bf(b[1]); r[6]=f2bf(b[2]); r[7]=f2bf(b[3]);
    return r;
}

// ---------- W -> MFMA-fragment-linear layout (unchanged) ----------
__global__ __launch_bounds__(256) void wconv_kernel(
    const float* __restrict__ Wq, const float* __restrict__ Wk,
    const float* __restrict__ Wv, __hip_bfloat16* __restrict__ Wfrag)
{
    const int g = blockIdx.x*256 + threadIdx.x;   // [0, 24576)
    const int l = g & 63;
    const int ntg = (g >> 6) % 6;
    const int cg = g / 384;
    const int n = ntg*32 + (l & 31);
    const int m = n >> 6;
    const int ncol = n & 63;
    const float* W = (m==0) ? Wq : (m==1) ? Wk : Wv;
    const float sc = (m==0) ? QSCALE : 1.0f;
    const int k0 = cg*16 + (l>>5)*8;
    bf16x8 r;
    #pragma unroll
    for (int j=0;j<8;++j)
        r[j] = f2bf(W[(size_t)(k0+j)*64 + ncol] * sc);
    *reinterpret_cast<bf16x8*>(Wfrag + (size_t)g*8) = r;
}

// ---------- QKV projection v4 (UNCHANGED from R7) ----------
__global__ __launch_bounds__(384, 3) void proj_kernel(
    const float* __restrict__ x, const __hip_bfloat16* __restrict__ Wfrag,
    __hip_bfloat16* __restrict__ Qo, __hip_bfloat16* __restrict__ Ko,
    __hip_bfloat16* __restrict__ VTg)
{
    __shared__ __align__(16) unsigned short xs[2][32*64];
    __shared__ float vt[32*65];
    const int tid = threadIdx.x;
    const int w = tid>>6, l = tid&63;
    const int l31 = l&31, kg = l>>5;
    const float* xp = x + (size_t)blockIdx.x*32*E_;

    f32x16 acc;
    #pragma unroll
    for (int j=0;j<16;++j) acc[j]=0.f;

    const bf16x8* Wfp = reinterpret_cast<const bf16x8*>(Wfrag);

    bf16x8 btA[4], btB[4];
    #pragma unroll
    for (int c=0;c<4;++c)
        btA[c] = Wfp[(size_t)(((0*4+c)*6 + w)*64 + l)];

    const int srow = tid>>3, sc8 = tid&7;

    if (tid < 256){
        f32x4 v0 = *reinterpret_cast<const f32x4*>(xp + (size_t)srow*E_ + sc8*8);
        f32x4 v1 = *reinterpret_cast<const f32x4*>(xp + (size_t)srow*E_ + sc8*8 + 4);
        *reinterpret_cast<bf16x8*>((char*)&xs[0][0] + srow*128 + ((sc8*16) ^ ((srow&7)<<4))) = cvt8v(v0, v1);
    }
    __syncthreads();

#define PSTEP(T, BC, BN)                                                       \
    {                                                                          \
        const int t = (T);                                                     \
        if (t+1 < 16){                                                         \
            _Pragma("unroll")                                                  \
            for (int c=0;c<4;++c)                                              \
                BN[c] = Wfp[(size_t)((((t+1)*4+c)*6 + w)*64 + l)];             \
        }                                                                      \
        f32x4 xa0, xa1;                                                        \
        if (t+1 < 16 && tid < 256){                                            \
            xa0 = *reinterpret_cast<const f32x4*>(xp + (size_t)srow*E_ + (t+1)*64 + sc8*8);     \
            xa1 = *reinterpret_cast<const f32x4*>(xp + (size_t)srow*E_ + (t+1)*64 + sc8*8 + 4); \
        }                                                                      \
        const char* xb = (const char*)&xs[t&1][0];                             \
        _Pragma("unroll")                                                      \
        for (int c=0;c<4;++c){                                                 \
            bf16x8 af = *reinterpret_cast<const bf16x8*>(xb + l31*128 + (((c*32 + kg*16)) ^ ((l31&7)<<4))); \
            acc = __builtin_amdgcn_mfma_f32_32x32x16_bf16(af, BC[c], acc, 0,0,0); \
        }                                                                      \
        if (t+1 < 16){                                                         \
            if (tid < 256)                                                     \
                *reinterpret_cast<bf16x8*>((char*)&xs[(t+1)&1][0] + srow*128 + ((sc8*16) ^ ((srow&7)<<4))) = cvt8v(xa0, xa1); \
            __syncthreads();                                                   \
        }                                                                      \
    }

    for (int t2=0; t2<8; ++t2){
        PSTEP(2*t2,   btA, btB)
        PSTEP(2*t2+1, btB, btA)
    }
#undef PSTEP

    const size_t rowBase = (size_t)blockIdx.x*32;
    const int mat = w>>1;
    const int col = (w&1)*32 + l31;
    if (mat < 2){
        __hip_bfloat16* dst = (mat==0) ? Qo : Ko;
        #pragma unroll
        for (int reg=0; reg<16; ++reg){
            const int mr = (reg&3) + 8*(reg>>2) + 4*kg;
            dst[(rowBase + mr)*64 + col] = __float2bfloat16(acc[reg]);
        }
    }
    if (mat == 2){
        #pragma unroll
        for (int reg=0; reg<16; ++reg){
            const int mr = (reg&3) + 8*(reg>>2) + 4*kg;
            vt[mr*65 + col] = acc[reg];
        }
    }
    __syncthreads();
    if (tid < 256){
        const int bb = blockIdx.x >> 6;
        const int t0 = (blockIdx.x & 63)*32;
        const int d = tid>>2, rseg = tid&3;
        bf16x8 pk;
        #pragma unroll
        for (int j=0;j<8;++j)
            pk[j] = f2bf(vt[(rseg*8+j)*65 + d]);
        *reinterpret_cast<bf16x8*>(VTg + (size_t)bb*64*T_ + (size_t)d*T_ + t0 + rseg*8) = pk;
    }
}

// ---------- repack: Q/K/V^T -> MFMA-fragment-linear (coalesced fattn loads) ----------
// Kfrag 16B-block idx: (((b*32+t)*4+nt)*2+ks)*64 + l  holds K[b,t*64+nt*16+(l&15)][ks*32+(l>>4)*8+j]
// Vfrag 16B-block idx: (((b*32+t)*4+dt)*2+ks)*64 + l  holds VT[b][dt*16+(l&15)][t*64+ks*32+(l>>4)*8+j]
// Qfrag 16B-block idx: ((b*128+s)*2+ks)*64 + l        holds Q[b,s*16+(l&15)][ks*32+(l>>4)*8+j]
__global__ __launch_bounds__(256) void repack_kernel(
    const __hip_bfloat16* __restrict__ Qb, const __hip_bfloat16* __restrict__ Kb,
    const __hip_bfloat16* __restrict__ VTb,
    __hip_bfloat16* __restrict__ Qfrag, __hip_bfloat16* __restrict__ Kfrag,
    __hip_bfloat16* __restrict__ Vfrag)
{
    const int blk = blockIdx.x;
    const int tid = threadIdx.x;
    if (blk < 512){
        const int g = blk*256 + tid;            // 131072
        const int l = g & 63, ks = (g>>6)&1, nt = (g>>7)&3, t = (g>>9)&31, b = g>>14;
        const int l15 = l&15, lg = l>>4;
        bf16x8 v = *reinterpret_cast<const bf16x8*>(
            Kb + ((size_t)b*T_ + t*64 + nt*16 + l15)*64 + ks*32 + lg*8);
        *reinterpret_cast<bf16x8*>(Kfrag + (size_t)g*8) = v;
    } else if (blk < 1024){
        const int g = (blk-512)*256 + tid;      // 131072
        const int l = g & 63, ks = (g>>6)&1, dt = (g>>7)&3, t = (g>>9)&31, b = g>>14;
        const int l15 = l&15, lg = l>>4;
        bf16x8 v = *reinterpret_cast<const bf16x8*>(
            VTb + (size_t)b*64*T_ + (size_t)(dt*16 + l15)*T_ + t*64 + ks*32 + lg*8);
        *reinterpret_cast<bf16x8*>(Vfrag + (size_t)g*8) = v;
    } else {
        const int g = (blk-1024)*256 + tid;     // 131072
        const int l = g & 63, ks = (g>>6)&1, s = (g>>7)&127, b = g>>14;
        const int l15 = l&15, lg = l>>4;
        bf16x8 v = *reinterpret_cast<const bf16x8*>(
            Qb + ((size_t)b*T_ + s*16 + l15)*64 + ks*32 + lg*8);
        *reinterpret_cast<bf16x8*>(Qfrag + (size_t)g*8) = v;
    }
}

// ---------- flash attention v5: v4 structure, frag-linear coalesced loads ----------
__global__ __launch_bounds__(256, 2) void fattn_kernel(
    const __hip_bfloat16* __restrict__ Qfrag, const __hip_bfloat16* __restrict__ Kfrag,
    const __hip_bfloat16* __restrict__ Vfrag, float* __restrict__ out)
{
    __shared__ __align__(16) unsigned short Pl[4][16*64];
    __shared__ float Morg[4][2][16];
    __shared__ float Lorg[4][2][16];
    __shared__ __align__(16) float Oorg[4][2][16*64];

    const int tid = threadIdx.x;
    const int w = tid>>6, l = tid&63;
    const int l15 = l&15, lg = l>>4;

    const int b = blockIdx.x & 7;          // XCD-batch affinity
    const int p = blockIdx.x >> 3;         // 0..63
    const int sA = p, sB = 127 - p;
    const int nA = (sA>>2) + 1, nB = (sB>>2) + 1;
    const int NU = nA + nB;                // == 33
    const size_t batchoff = (size_t)b * T_ * 64;

    const bf16x8* qfp = reinterpret_cast<const bf16x8*>(Qfrag);
    const bf16x8* kfp = reinterpret_cast<const bf16x8*>(Kfrag);
    const bf16x8* vfp = reinterpret_cast<const bf16x8*>(Vfrag);
    char* pw = (char*)&Pl[w][0];

    const int qrA = sA*16 + l15, qrB = sB*16 + l15;
    const bf16x8 qA0 = qfp[(size_t)((b*128 + sA)*2 + 0)*64 + l];
    const bf16x8 qA1 = qfp[(size_t)((b*128 + sA)*2 + 1)*64 + l];
    const bf16x8 qB0 = qfp[(size_t)((b*128 + sB)*2 + 0)*64 + l];
    const bf16x8 qB1 = qfp[(size_t)((b*128 + sB)*2 + 1)*64 + l];

    f32x4 oA[4], oB[4];
    #pragma unroll
    for (int i=0;i<4;++i){ oA[i] = (f32x4){0.f,0.f,0.f,0.f}; oB[i] = (f32x4){0.f,0.f,0.f,0.f}; }
    float mA = -1e30f, lA = 0.f, mB = -1e30f, lB = 0.f;

    bf16x8 kf[8], vf[8];

    {
        const int u0 = w;
        const int kvt = (u0 < nA ? u0 : u0 - nA);
        #pragma unroll
        for (int ks=0;ks<2;++ks)
            #pragma unroll
            for (int nt=0;nt<4;++nt)
                kf[ks*4+nt] = kfp[(size_t)(((b*32 + kvt)*4 + nt)*2 + ks)*64 + l];
    }

    auto body = [&](f32x4 (&o)[4], float &mrun, float &lrun,
                    const bf16x8 &qf0, const bf16x8 &qf1,
                    int qrow, int kv0, bool diag, bool hasN, int kvtn)
    {
        f32x4 s4[4];
        #pragma unroll
        for (int nt=0;nt<4;++nt) s4[nt] = (f32x4){0.f,0.f,0.f,0.f};
        __builtin_amdgcn_s_setprio(1);
        #pragma unroll
        for (int ks=0;ks<2;++ks){
            const bf16x8 qf = ks ? qf1 : qf0;
            #pragma unroll
            for (int nt=0;nt<4;++nt)
                s4[nt] = __builtin_amdgcn_mfma_f32_16x16x32_bf16(kf[ks*4+nt], qf, s4[nt], 0,0,0);
        }
        __builtin_amdgcn_s_setprio(0);

        if (hasN){
            #pragma unroll
            for (int ks=0;ks<2;++ks)
                #pragma unroll
                for (int nt=0;nt<4;++nt)
                    kf[ks*4+nt] = kfp[(size_t)(((b*32 + kvtn)*4 + nt)*2 + ks)*64 + l];
        }

        if (diag){
            #pragma unroll
            for (int nt=0;nt<4;++nt)
                #pragma unroll
                for (int rr=0;rr<4;++rr){
                    const int kv = kv0 + nt*16 + lg*4 + rr;
                    if (kv > qrow) s4[nt][rr] = -1e30f;
                }
        }

        float pm;
        {
            float m0 = fmaxf(fmaxf(s4[0][0],s4[0][1]), fmaxf(s4[0][2],s4[0][3]));
            float m1 = fmaxf(fmaxf(s4[1][0],s4[1][1]), fmaxf(s4[1][2],s4[1][3]));
            float m2 = fmaxf(fmaxf(s4[2][0],s4[2][1]), fmaxf(s4[2][2],s4[2][3]));
            float m3 = fmaxf(fmaxf(s4[3][0],s4[3][1]), fmaxf(s4[3][2],s4[3][3]));
            pm = fmaxf(fmaxf(m0,m1), fmaxf(m2,m3));
        }
        pm = fmaxf(pm, __shfl_xor(pm, 16));
        pm = fmaxf(pm, __shfl_xor(pm, 32));
        if (pm > mrun + 8.0f){
            const float scl = exp2f(mrun - pm);
            mrun = pm; lrun *= scl;
            #pragma unroll
            for (int dt=0;dt<4;++dt)
                #pragma unroll
                for (int j=0;j<4;++j) o[dt][j] *= scl;
        }
        float rs = 0.f;
        #pragma unroll
        for (int nt=0;nt<4;++nt)
            #pragma unroll
            for (int rr=0;rr<4;++rr){
                const float pv = exp2f(s4[nt][rr] - mrun);
                s4[nt][rr] = pv; rs += pv;
            }
        rs += __shfl_xor(rs, 16);
        rs += __shfl_xor(rs, 32);
        lrun += rs;

        #pragma unroll
        for (int nt=0;nt<4;++nt){
            u16x4 pk;
            #pragma unroll
            for (int rr=0;rr<4;++rr) pk[rr] = (unsigned short)f2bf(s4[nt][rr]);
            *reinterpret_cast<u16x4*>(pw + l15*128 + ((nt*32 + lg*8) ^ ((l15&7)<<4))) = pk;
        }

        __builtin_amdgcn_s_setprio(1);
        #pragma unroll
        for (int ks=0;ks<2;++ks){
            bf16x8 pf = *reinterpret_cast<const bf16x8*>(pw + l15*128 + ((ks*64 + lg*16) ^ ((l15&7)<<4)));
            #pragma unroll
            for (int dt=0;dt<4;++dt)
                o[dt] = __builtin_amdgcn_mfma_f32_16x16x32_bf16(vf[ks*4+dt], pf, o[dt], 0,0,0);
        }
        __builtin_amdgcn_s_setprio(0);
    };

    for (int u = w; u < NU; u += 4){
        const bool isA = (u < nA);
        const int kvt = isA ? u : (u - nA);
        const int kv0 = kvt*64;
        const bool diag = isA ? (kvt == nA-1) : (kvt == nB-1);

        #pragma unroll
        for (int ks=0;ks<2;++ks)
            #pragma unroll
            for (int dt=0;dt<4;++dt)
                vf[ks*4+dt] = vfp[(size_t)(((b*32 + kvt)*4 + dt)*2 + ks)*64 + l];

        const int un = u + 4;
        const bool hasN = un < NU;
        const int kvtn = hasN ? (un < nA ? un : un - nA) : 0;

        if (isA) body(oA, mA, lA, qA0, qA1, qrA, kv0, diag, hasN, kvtn);
        else     body(oB, mB, lB, qB0, qB1, qrB, kv0, diag, hasN, kvtn);
    }

    #pragma unroll
    for (int dt=0;dt<4;++dt){
        *reinterpret_cast<f32x4*>(&Oorg[w][0][l15*64 + dt*16 + lg*4]) = oA[dt];
        *reinterpret_cast<f32x4*>(&Oorg[w][1][l15*64 + dt*16 + lg*4]) = oB[dt];
    }
    if (lg == 0){
        Morg[w][0][l15] = mA; Lorg[w][0][l15] = lA;
        Morg[w][1][l15] = mB; Lorg[w][1][l15] = lB;
    }
    __syncthreads();
    {
        const int h = tid>>7, q = (tid>>3)&15, d0 = (tid&7)*8;
        const float m0=Morg[0][h][q], m1=Morg[1][h][q], m2=Morg[2][h][q], m3=Morg[3][h][q];
        const float M = fmaxf(fmaxf(m0,m1), fmaxf(m2,m3));
        const float a0=exp2f(m0-M), a1=exp2f(m1-M), a2=exp2f(m2-M), a3=exp2f(m3-M);
        const float L = a0*Lorg[0][h][q] + a1*Lorg[1][h][q] + a2*Lorg[2][h][q] + a3*Lorg[3][h][q];
        const float inv = 1.0f / L;
        const int s = h ? sB : sA;
        float* op = out + batchoff + (size_t)(s*16 + q)*64 + d0;
        #pragma unroll
        for (int j=0;j<8;++j){
            const float v = a0*Oorg[0][h][q*64+d0+j] + a1*Oorg[1][h][q*64+d0+j]
                          + a2*Oorg[2][h][q*64+d0+j] + a3*Oorg[3][h][q*64+d0+j];
            op[j] = v * inv;
        }
    }
}

extern "C" void kernel_launch(void* const* d_in, const int* in_sizes, int n_in,
                              void* d_out, int out_size, void* d_ws, size_t ws_size,
                              hipStream_t stream) {
    const float* x  = (const float*)d_in[0];
    const float* Wq = (const float*)d_in[1];
    const float* Wk = (const float*)d_in[2];
    const float* Wv = (const float*)d_in[3];
    float* out = (float*)d_out;

    const size_t NTOK = (size_t)B_*T_*64;   // 1M elems per tensor
    __hip_bfloat16* Wfrag = (__hip_bfloat16*)d_ws;      // 384 KB
    __hip_bfloat16* Qb    = Wfrag + (size_t)24576*8;    // [B*T,64] (pre-scaled)
    __hip_bfloat16* Kb    = Qb + NTOK;                  // [B*T,64]
    __hip_bfloat16* VTb   = Kb + NTOK;                  // [B][64][T]
    __hip_bfloat16* Qfrag = VTb + NTOK;
    __hip_bfloat16* Kfrag = Qfrag + NTOK;
    __hip_bfloat16* Vfrag = Kfrag + NTOK;

    wconv_kernel<<<96, 256, 0, stream>>>(Wq, Wk, Wv, Wfrag);
    proj_kernel<<<512, 384, 0, stream>>>(x, Wfrag, Qb, Kb, VTb);
    repack_kernel<<<1536, 256, 0, stream>>>(Qb, Kb, VTb, Qfrag, Kfrag, Vfrag);
    fattn_kernel<<<512, 256, 0, stream>>>(Qfrag, Kfrag, Vfrag, out);
}